// Round 1
// baseline (166.401 us; speedup 1.0000x reference)
//
#include <hip/hip_runtime.h>
#include <hip/hip_bf16.h>
#include <cstddef>

// Problem constants (reference: B=128, IN=1024, H=1024, TAU=1.0)
#define B_DIM  128
#define IN_DIM 1024
#define H_DIM  1024

constexpr float kInvTau  = 1.0f;            // 1 / TAU
constexpr float kDecay   = 1.0f - 0.01f;    // 1 - FAST_WEIGHT_DECAY
constexpr float kLrOverB = 0.01f / 128.0f;  // FAST_WEIGHT_LR / B

// ---------------------------------------------------------------------------
// Kernel A: fused  input-GEMM + gumbel-softmax-reduce + tanh  -> h_next
//   grid = (H, B/32), block = 256 threads (4 waves)
//   block (o, bc): wave w handles rows b = bc*32 + bi*4 + w, bi = 0..7
//   Each wave processes one (b, o) row of length 1024: 64 lanes x 16 elems.
// ---------------------------------------------------------------------------
__global__ __launch_bounds__(256) void fused_rows(
    const float* __restrict__ x_t,     // (B, IN)
    const float* __restrict__ h_prev,  // (B, H)
    const float* __restrict__ W_ih,    // (H, IN)
    const float* __restrict__ b_ih,    // (H,)
    const float* __restrict__ W_f,     // (H, H)
    const float* __restrict__ W_v,     // (H, H)
    const float* __restrict__ gu,      // (B, H, H)
    float* __restrict__ h_next)        // (B, H)  [= d_out region 0]
{
    const int o  = blockIdx.x;
    const int bc = blockIdx.y;
    const int t  = threadIdx.x;

    __shared__ __align__(16) float lrow[H_DIM];  // (W_f + W_v) row o
    __shared__ __align__(16) float wrow[H_DIM];  // W_ih row o

    // Stage the two per-o rows into LDS (256 threads x 1 float4 each).
    {
        const float4 a = reinterpret_cast<const float4*>(W_f + (size_t)o * H_DIM)[t];
        const float4 b = reinterpret_cast<const float4*>(W_v + (size_t)o * H_DIM)[t];
        float4 s;
        s.x = a.x + b.x; s.y = a.y + b.y; s.z = a.z + b.z; s.w = a.w + b.w;
        reinterpret_cast<float4*>(lrow)[t] = s;
        reinterpret_cast<float4*>(wrow)[t] =
            reinterpret_cast<const float4*>(W_ih + (size_t)o * IN_DIM)[t];
    }
    __syncthreads();

    const float bias = b_ih[o];
    const int w = t >> 6, lane = t & 63;

    const float4* l4 = reinterpret_cast<const float4*>(lrow);
    const float4* w4 = reinterpret_cast<const float4*>(wrow);

    for (int bi = 0; bi < 8; ++bi) {
        const int b = bc * 32 + bi * 4 + w;

        const float4* g4  = reinterpret_cast<const float4*>(gu + ((size_t)b * H_DIM + o) * H_DIM);
        const float4* hp4 = reinterpret_cast<const float4*>(h_prev + (size_t)b * H_DIM);
        const float4* x4  = reinterpret_cast<const float4*>(x_t + (size_t)b * IN_DIM);

        float s[16], hp[16];
        float m  = -3.0e38f;
        float ic = 0.0f;

#pragma unroll
        for (int j = 0; j < 4; ++j) {
            const int idx = lane + 64 * j;        // float4 index; h = 4*idx .. 4*idx+3
            const float4 u  = g4[idx];
            const float4 l  = l4[idx];
            const float4 p  = hp4[idx];
            const float4 xv = x4[idx];
            const float4 wv = w4[idx];

            const float ub[4] = {u.x, u.y, u.z, u.w};
            const float lb[4] = {l.x, l.y, l.z, l.w};
            const float pb[4] = {p.x, p.y, p.z, p.w};
            const float xb[4] = {xv.x, xv.y, xv.z, xv.w};
            const float wb[4] = {wv.x, wv.y, wv.z, wv.w};

#pragma unroll
            for (int c = 0; c < 4; ++c) {
                const float uc  = fmaxf(ub[c], 1e-9f);          // clip (upper clip is a no-op in fp32)
                const float gmb = -__logf(-__logf(uc));         // Gumbel(0,1)
                const float sv  = (lb[c] * kInvTau + gmb) * kInvTau;
                s[4 * j + c]  = sv;
                hp[4 * j + c] = pb[c];
                m  = fmaxf(m, sv);
                ic = fmaf(xb[c], wb[c], ic);
            }
        }

        // Wave-wide reductions: max(s) and sum(x*w) together.
#pragma unroll
        for (int off = 32; off > 0; off >>= 1) {
            m  = fmaxf(m, __shfl_xor(m, off, 64));
            ic += __shfl_xor(ic, off, 64);
        }

        float sum = 0.0f, dot = 0.0f;
#pragma unroll
        for (int i = 0; i < 16; ++i) {
            const float e = __expf(s[i] - m);
            sum += e;
            dot = fmaf(e, hp[i], dot);
        }
#pragma unroll
        for (int off = 32; off > 0; off >>= 1) {
            sum += __shfl_xor(sum, off, 64);
            dot += __shfl_xor(dot, off, 64);
        }

        if (lane == 0) {
            h_next[(size_t)b * H_DIM + o] = tanhf(ic + bias + dot / sum);
        }
    }
}

// ---------------------------------------------------------------------------
// Kernel B: W_out = 0.99 * W_v + (0.01/B) * (h_next^T @ h_prev)
//   grid = (H/64, H/64), block = 256. 64(o) x 64(h) tile, K = B = 128 in LDS.
//   Thread (tx,ty) computes o = o0+4*ty..+3, h = h0+4*tx..+3 (float4 reads).
// ---------------------------------------------------------------------------
__global__ __launch_bounds__(256) void hebbian_update(
    const float* __restrict__ h_next,  // (B, H)
    const float* __restrict__ h_prev,  // (B, H)
    const float* __restrict__ W_v,     // (H, H)
    float* __restrict__ W_out)         // (H, H)  [= d_out region 1]
{
    const int h0 = blockIdx.x * 64;
    const int o0 = blockIdx.y * 64;
    const int t  = threadIdx.x;

    __shared__ __align__(16) float hn_s[B_DIM][64];  // 32 KB
    __shared__ __align__(16) float hp_s[B_DIM][64];  // 32 KB

#pragma unroll
    for (int i = 0; i < 32; ++i) {
        const int e  = t + 256 * i;
        const int bb = e >> 6;
        const int cc = e & 63;
        hn_s[bb][cc] = h_next[(size_t)bb * H_DIM + o0 + cc];
        hp_s[bb][cc] = h_prev[(size_t)bb * H_DIM + h0 + cc];
    }
    __syncthreads();

    const int tx = t & 15;   // h group
    const int ty = t >> 4;   // o group

    float acc[4][4] = {{0.f}};

#pragma unroll 8
    for (int b = 0; b < B_DIM; ++b) {
        const float4 av = reinterpret_cast<const float4*>(hn_s[b])[ty];
        const float4 bv = reinterpret_cast<const float4*>(hp_s[b])[tx];
        const float aa[4] = {av.x, av.y, av.z, av.w};
        const float bb[4] = {bv.x, bv.y, bv.z, bv.w};
#pragma unroll
        for (int a = 0; a < 4; ++a)
#pragma unroll
            for (int c = 0; c < 4; ++c)
                acc[a][c] = fmaf(aa[a], bb[c], acc[a][c]);
    }

#pragma unroll
    for (int a = 0; a < 4; ++a) {
        const int o = o0 + 4 * ty + a;
        const size_t base = (size_t)o * H_DIM + h0 + 4 * tx;
        const float4 wv = *reinterpret_cast<const float4*>(W_v + base);
        float4 r;
        r.x = wv.x * kDecay + acc[a][0] * kLrOverB;
        r.y = wv.y * kDecay + acc[a][1] * kLrOverB;
        r.z = wv.z * kDecay + acc[a][2] * kLrOverB;
        r.w = wv.w * kDecay + acc[a][3] * kLrOverB;
        *reinterpret_cast<float4*>(W_out + base) = r;
    }
}

// ---------------------------------------------------------------------------
extern "C" void kernel_launch(void* const* d_in, const int* in_sizes, int n_in,
                              void* d_out, int out_size, void* d_ws, size_t ws_size,
                              hipStream_t stream)
{
    const float* x_t    = (const float*)d_in[0];
    const float* h_prev = (const float*)d_in[1];
    const float* W_ih   = (const float*)d_in[2];
    const float* b_ih   = (const float*)d_in[3];
    const float* W_f    = (const float*)d_in[4];
    const float* W_v    = (const float*)d_in[5];
    const float* gu     = (const float*)d_in[6];

    float* out    = (float*)d_out;
    float* h_next = out;                               // (B, H)
    float* W_out  = out + (size_t)B_DIM * H_DIM;       // (H, H)

    fused_rows<<<dim3(H_DIM, B_DIM / 32), 256, 0, stream>>>(
        x_t, h_prev, W_ih, b_ih, W_f, W_v, gu, h_next);

    hebbian_update<<<dim3(H_DIM / 64, H_DIM / 64), 256, 0, stream>>>(
        h_next, h_prev, W_v, W_out);
}